// Round 1
// 2830.509 us; speedup vs baseline: 1.1420x; 1.1420x over previous
//
#include <hip/hip_runtime.h>
#include <cstdint>

// Problem constants (from reference)
#define VN 100000   // vocab
#define DD 128      // D
#define BB 512      // batch
#define LL 20       // session length
#define TT 20       // time steps
#define HH 32       // H
#define CC 33       // C = H+1
#define NC (HH*CC)  // 1056

typedef unsigned int u32;

#define DEV static __device__ __forceinline__

DEV float tanh_fast(float x){ float e=__expf(2.f*x); return 1.f - 2.f/(e+1.f); }

// broadcast a lane's value wave-wide via v_readlane -> SGPR (folds into v_fma scalar src)
DEV float rdlane(float v, int l){
  return __int_as_float(__builtin_amdgcn_readlane(__float_as_int(v), l));
}

// ================= K1: fused knots + CDE RK4 scan, w2-in-registers =========
// g=2 batch rows/block, 256 blocks (full 256-CU coverage), 576 threads (9 waves).
// Threads 0..511: thread (h=t>>4, q=t&15) owns w2 rows n = h*33 + {2q, 2q+1} in
// VGPRs (256 f32). Wave 8 (t>=512): lane l owns tail row n = (l&31)*33 + 32 for
// g = l>>5. Per RK4 stage, h1 is broadcast via v_readlane (no LDS-pipe serial
// cost), so stage B is pure register FMA. w2 is read from L2 exactly once.
__global__ __launch_bounds__(576) void k_cde(
    const float* __restrict__ emb, const int* __restrict__ eids,
    const float* __restrict__ times,
    const float* __restrict__ red_w, const float* __restrict__ red_b,
    const float* __restrict__ w1, const float* __restrict__ b1,
    const float* __restrict__ w2, const float* __restrict__ b2,
    const float* __restrict__ iw, const float* __restrict__ ib,
    const float* __restrict__ rw, const float* __restrict__ rb,
    float* __restrict__ te){
  __shared__ float s_u[40*DD + 32*129];  // phase1: er(5120)|rw(4128); phase2: w1 padded (128*33)
  __shared__ float s_X[2*TT*CC];         // [g][t][c], persistent (5.3 KB)
  __shared__ float s_b1[DD];
  __shared__ float s_h1[2*DD];           // [g][j]
  __shared__ float s_z[64], s_zs[64], s_ks[64], s_kp[64], s_kt[64];
  __shared__ float s_dx[2*CC];
  const int t = threadIdx.x;
  const int b0 = blockIdx.x*2;
  const int lane = t & 63;
  float* s_er = s_u;
  float* s_rw = s_u + 40*DD;             // phase1, rows padded to 129
  float* s_w1 = s_u;                     // phase2 alias, rows padded to 33

  // ---- w2 rows -> registers (issued first; overlaps phase-1 knot build) ----
  float w2a[DD], w2b[DD];
  float b2a, b2b;
  int hq=0, qq=0;
  if (t < 512){
    hq = t>>4; qq = t&15;
    const int n0 = hq*CC + 2*qq;
    const float4* r0=(const float4*)(w2+(size_t)n0*DD);
    const float4* r1=(const float4*)(w2+(size_t)(n0+1)*DD);
    #pragma unroll 32
    for(int j=0;j<32;j++){
      float4 a=r0[j];
      w2a[4*j]=a.x; w2a[4*j+1]=a.y; w2a[4*j+2]=a.z; w2a[4*j+3]=a.w;
    }
    #pragma unroll 32
    for(int j=0;j<32;j++){
      float4 bv=r1[j];
      w2b[4*j]=bv.x; w2b[4*j+1]=bv.y; w2b[4*j+2]=bv.z; w2b[4*j+3]=bv.w;
    }
    b2a=b2[n0]; b2b=b2[n0+1];
  } else {
    const int l=t-512; const int nt=(l&31)*CC+32;
    const float4* r0=(const float4*)(w2+(size_t)nt*DD);
    #pragma unroll 32
    for(int j=0;j<32;j++){
      float4 a=r0[j];
      w2a[4*j]=a.x; w2a[4*j+1]=a.y; w2a[4*j+2]=a.z; w2a[4*j+3]=a.w;
    }
    b2a=b2[nt]; b2b=0.f;   // w2b unused in tail lanes
  }

  // ---- phase 1: knots X[g][t][:] ----
  for (int i=t;i<HH*DD;i+=576){ int hh=i>>7, d=i&127; s_rw[hh*129+d]=red_w[i]; }
  if (t<40){ int g=t/TT, tt2=t%TT; s_X[(g*TT+tt2)*CC]=times[(b0+g)*TT+tt2]; }
  for (int p=t;p<40*DD;p+=576){ int r=p>>7, e=p&127;
      s_er[p]=emb[(size_t)eids[b0*TT + r]*DD + e]; }
  __syncthreads();
  for (int task=t; task<40*HH; task+=576){   // 576%32==0 -> shuffle groups aligned
    int r=task>>5, hh=task&31;
    const float* wr=s_rw+hh*129;
    const float* er=s_er+(size_t)r*DD;
    float acc=red_b[hh];
    #pragma unroll 16
    for(int e=0;e<DD;e++) acc += er[e]*wr[e];
    float ss=acc*acc;
    #pragma unroll
    for(int o=16;o>0;o>>=1) ss+=__shfl_xor(ss,o,32);
    s_X[r*CC+1+hh]=acc/(sqrtf(ss)+1e-12f);    // fode = l2n(...) into X[...,1+h]
  }
  __syncthreads();                            // fode readers done; union free
  // ---- phase 2 weights: w1 (padded stride 33: bank-conflict-free), b1 ----
  for (int i=t;i<DD*HH;i+=576){ int j=i>>5, hh=i&31; s_w1[j*33+hh]=w1[i]; }
  if (t<DD) s_b1[t]=b1[t];
  // ---- z0 = X[:,0] @ init_w.T + init_b ----
  if (t<64){
    int g=t>>5, hh=t&31;
    float acc=ib[hh];
    const float* x0=s_X+(size_t)(g*TT)*CC;
    #pragma unroll
    for(int c=0;c<CC;c++) acc += x0[c]*iw[hh*CC+c];
    s_z[t]=acc; s_zs[t]=acc;
  }

  for (int step=0; step<TT-1; step++){
    __syncthreads();
    if (t<2*CC){ int g=t/CC, c=t-g*CC;
      s_dx[t]=s_X[(g*TT+step+1)*CC+c]-s_X[(g*TT+step)*CC+c]; }
    __syncthreads();
    float dx00=0.f,dx01=0.f,dx10=0.f,dx11=0.f,dxt=0.f;
    if (t<512){ int c0=2*qq;
      dx00=s_dx[c0]; dx01=s_dx[c0+1]; dx10=s_dx[CC+c0]; dx11=s_dx[CC+c0+1];
    } else { int l=t-512; dxt=s_dx[(l>>5)*CC+32]; }

    for (int s=0;s<4;s++){
      // ---- stage A: h1 = relu(zs @ w1.T + b1)  (zs broadcast via readlane) ----
      if (t<256){
        const int g=t>>7, j=t&127, gb=(t>>7)*32;
        float zsv=s_zs[lane];
        float acc=s_b1[j];
        const float* wj=s_w1+j*33;
        #pragma unroll 32
        for(int hh=0;hh<32;hh++) acc += rdlane(zsv, gb+hh)*wj[hh];
        s_h1[g*DD+j]=fmaxf(acc,0.f);
      }
      __syncthreads();
      // every wave pulls h1 into lane regs (4 conflict-free ds_read_b32)
      float h00=s_h1[lane],    h01=s_h1[64+lane];      // g=0: j=lane, 64+lane
      float h10=s_h1[DD+lane], h11=s_h1[DD+64+lane];   // g=1
      if (t<512){
        // ---- stage B: o2 rows from registers; h1 broadcast via readlane ----
        float a00=b2a, a10=b2b, a01=b2a, a11=b2b;      // acc[row][g]
        #pragma unroll 64
        for(int j=0;j<64;j++){
          float s0=rdlane(h00,j), s1=rdlane(h10,j);
          a00+=s0*w2a[j]; a10+=s0*w2b[j];
          a01+=s1*w2a[j]; a11+=s1*w2b[j];
        }
        #pragma unroll 64
        for(int j=0;j<64;j++){
          float s0=rdlane(h01,j), s1=rdlane(h11,j);
          a00+=s0*w2a[64+j]; a10+=s0*w2b[64+j];
          a01+=s1*w2a[64+j]; a11+=s1*w2b[64+j];
        }
        float pk0=tanh_fast(a00)*dx00 + tanh_fast(a10)*dx01;  // g=0, c={c0,c0+1}
        float pk1=tanh_fast(a01)*dx10 + tanh_fast(a11)*dx11;  // g=1
        #pragma unroll
        for(int o=8;o>0;o>>=1){
          pk0+=__shfl_xor(pk0,o,16);
          pk1+=__shfl_xor(pk1,o,16);
        }
        if (qq==0){ s_kp[hq]=pk0; s_kp[32+hq]=pk1; }
      } else {
        // ---- tail wave: rows n = h*33+32, one (g,h) per lane ----
        const int l=t-512, gq=l>>5, ht=l&31;
        float a0=0.f, a1=0.f;
        #pragma unroll 64
        for(int j=0;j<64;j++){
          a0+=rdlane(h00,j)*w2a[j];
          a1+=rdlane(h10,j)*w2a[j];
        }
        #pragma unroll 64
        for(int j=0;j<64;j++){
          a0+=rdlane(h01,j)*w2a[64+j];
          a1+=rdlane(h11,j)*w2a[64+j];
        }
        float av = b2a + (gq ? a1 : a0);
        s_kt[gq*32+ht]=tanh_fast(av)*dxt;
      }
      __syncthreads();
      // ---- RK4 bookkeeping: one thread per (g,h) ----
      if (t<64){
        float k=s_kp[t]+s_kt[t];
        float zv=s_z[t];
        if(s==0){ s_ks[t]=k;        s_zs[t]=zv+0.5f*k; }
        else if(s==1){ s_ks[t]+=2.f*k; s_zs[t]=zv+0.5f*k; }
        else if(s==2){ s_ks[t]+=2.f*k; s_zs[t]=zv+k; }
        else { float zn=zv+(s_ks[t]+k)*(1.f/6.f); s_z[t]=zn; s_zs[t]=zn; }
      }
      __syncthreads();
    }
  }
  // ---- epilogue: time_embeds = zT @ rec_w.T + rec_b ----
  if (t<256){
    const int g=t>>7, d=t&127;
    float acc=rb[d];
    const float* zz=s_z+g*HH;
    const float4* rv=(const float4*)(rw + (size_t)d*HH);
    #pragma unroll 8
    for(int jj=0;jj<8;jj++){
      float4 vv=rv[jj];
      acc += zz[4*jj]*vv.x + zz[4*jj+1]*vv.y + zz[4*jj+2]*vv.z + zz[4*jj+3]*vv.w;
    }
    te[(size_t)(b0+g)*DD+d]=acc;
  }
}

// ================= K2: attention readout + sr (featn recomputed) ===========
__global__ __launch_bounds__(128) void k_attn(
    const float* __restrict__ emb, const int* __restrict__ iid,
    const int* __restrict__ last_nodes,
    const float* __restrict__ fcu_w, const float* __restrict__ fcv_w,
    const float* __restrict__ fcv_b, const float* __restrict__ fce_w,
    const float* __restrict__ fcsr_w,
    const float* __restrict__ te, float* __restrict__ sr){
  __shared__ float s_fn[LL*DD];      // featn tile = x/||x||
  __shared__ float s_inv[LL];
  __shared__ float s_e[LL], s_alpha[LL], s_red[2], s_sg[DD], s_fl[DD];
  const int t=threadIdx.x, b=blockIdx.x;
  for(int p=t;p<LL*DD;p+=128){
    int r=p>>7, e=p&127;
    s_fn[p]=emb[(size_t)iid[b*LL+r]*DD+e];
  }
  __syncthreads();
  { int w=t>>6, lane=t&63;
    for(int r=w;r<LL;r+=2){
      float a=s_fn[r*DD+lane], c=s_fn[r*DD+lane+64];
      float s=a*a+c*c;
      #pragma unroll
      for(int o=32;o>0;o>>=1) s+=__shfl_xor(s,o,64);
      if(lane==0) s_inv[r]=1.f/sqrtf(s);
    }
  }
  __syncthreads();
  for(int p=t;p<LL*DD;p+=128) s_fn[p]*=s_inv[p>>7];
  __syncthreads();
  int lr=last_nodes[b]-b*LL; if(lr<0||lr>=LL) lr=LL-1;   // == L-1 by construction
  s_fl[t]=s_fn[lr*DD+t];
  __syncthreads();
  float fv;
  {
    float acc=fcv_b[t];
    const float* wv=fcv_w + t*DD;
    #pragma unroll 8
    for(int j=0;j<DD;j++) acc += s_fl[j]*wv[j];
    fv=acc;
  }
  const float fce=fce_w[t];
  const float* wu=fcu_w + t*DD;
  for(int n=0;n<LL;n++){
    float fu=0.f;
    #pragma unroll 8
    for(int j=0;j<DD;j++) fu += s_fn[n*DD+j]*wu[j];
    float sv = fce/(1.f+__expf(-(fu+fv)));   // sigmoid * fce_w[d]
    #pragma unroll
    for(int o=32;o>0;o>>=1) sv += __shfl_xor(sv,o,64);
    if((t&63)==0) s_red[t>>6]=sv;
    __syncthreads();
    if(t==0) s_e[n]=s_red[0]+s_red[1];
    __syncthreads();
  }
  if(t<64){ // softmax over the 20 session nodes
    float ev=(t<LL)? s_e[t] : -1e30f;
    float m=ev;
    #pragma unroll
    for(int o=32;o>0;o>>=1) m=fmaxf(m,__shfl_xor(m,o,64));
    float ex=(t<LL)? __expf(ev-m):0.f;
    float ssum=ex;
    #pragma unroll
    for(int o=32;o>0;o>>=1) ssum+=__shfl_xor(ssum,o,64);
    if(t<LL) s_alpha[t]=ex/ssum;
  }
  __syncthreads();
  float sg=0.f;
  for(int n=0;n<LL;n++) sg += s_alpha[n]*s_fn[n*DD+t];
  s_sg[t]=sg;
  __syncthreads();
  // sr = l2n([sr_l, sr_g] @ fcsr_w.T + te)
  float pre=te[(size_t)b*DD+t];
  const float* wsr=fcsr_w + t*2*DD;
  #pragma unroll 8
  for(int j=0;j<DD;j++) pre += s_fl[j]*wsr[j];
  #pragma unroll 8
  for(int j=0;j<DD;j++) pre += s_sg[j]*wsr[DD+j];
  float ss=pre*pre;
  #pragma unroll
  for(int o=32;o>0;o>>=1) ss+=__shfl_xor(ss,o,64);
  if((t&63)==0) s_red[t>>6]=ss;
  __syncthreads();
  float tot=s_red[0]+s_red[1];
  sr[(size_t)b*DD+t]=pre/(sqrtf(tot)+1e-12f);
}

// ================= K3: logits (f32 out), inline emb-row norm ===============
__global__ __launch_bounds__(256) void k_logits(
    const float* __restrict__ emb, const float* __restrict__ srr,
    float* __restrict__ out){
  const int v=blockIdx.x*256+threadIdx.x;
  if(v>=VN) return;
  const int bstart=blockIdx.y*256;
  float er[DD];
  {
    const float4* ev=(const float4*)emb + (size_t)v*32;
    #pragma unroll
    for(int j=0;j<32;j++){
      float4 u=ev[j];
      er[j*4+0]=u.x; er[j*4+1]=u.y; er[j*4+2]=u.z; er[j*4+3]=u.w;
    }
  }
  float nrm=0.f;
  #pragma unroll
  for(int d=0;d<DD;d++) nrm += er[d]*er[d];
  const float rn=12.f/(sqrtf(nrm)+1e-12f);
  for(int b=bstart;b<bstart+256;b++){
    const float* s=srr+(size_t)b*DD;        // wave-uniform -> scalar loads
    float acc=0.f;
    #pragma unroll
    for(int d=0;d<DD;d++) acc += er[d]*s[d];
    out[(size_t)b*VN+v]=acc*rn;
  }
}

// ================= K4: per-row logsumexp over V (online, f32) ==============
__global__ __launch_bounds__(256) void k_lse(const float* __restrict__ out,
                                             float* __restrict__ lse){
  const int b=blockIdx.x, t=threadIdx.x;
  const float4* rp=(const float4*)(out + (size_t)b*VN);
  float m=-1e30f, s=0.f;
  for(int i=t;i<VN/4;i+=256){
    float4 x=rp[i];
    float mx=fmaxf(fmaxf(x.x,x.y),fmaxf(x.z,x.w));
    if(mx>m){ s=s*__expf(m-mx); m=mx; }
    s += __expf(x.x-m)+__expf(x.y-m)+__expf(x.z-m)+__expf(x.w-m);
  }
  __shared__ float sm[256], ssb[256];
  sm[t]=m; ssb[t]=s;
  __syncthreads();
  for(int o=128;o>0;o>>=1){
    if(t<o){
      float m1=sm[t], m2=sm[t+o], s1=ssb[t], s2=ssb[t+o];
      float mm=fmaxf(m1,m2);
      sm[t]=mm; ssb[t]=s1*__expf(m1-mm)+s2*__expf(m2-mm);
    }
    __syncthreads();
  }
  if(t==0) lse[b]=sm[0]+logf(ssb[0]);
}

// ================= K5: out -= lse[b] (in place, float4) ====================
__global__ __launch_bounds__(256) void k_sub(float* __restrict__ out,
                                             const float* __restrict__ lse){
  const size_t i=(size_t)blockIdx.x*256+threadIdx.x;  // float4 index
  const int b=(int)((i*4)/VN);                         // VN%4==0: no row cross
  const float l=lse[b];
  float4* p=(float4*)out;
  float4 x=p[i];
  x.x-=l; x.y-=l; x.z-=l; x.w-=l;
  p[i]=x;
}

extern "C" void kernel_launch(void* const* d_in, const int* in_sizes, int n_in,
                              void* d_out, int out_size, void* d_ws, size_t ws_size,
                              hipStream_t stream){
  const float* emb    = (const float*)d_in[0];
  // d_in[1..6]: W1,W2,gru_* — dead code in the reference, never read
  const float* fcu_w  = (const float*)d_in[7];
  const float* fcv_w  = (const float*)d_in[8];
  const float* fcv_b  = (const float*)d_in[9];
  const float* fce_w  = (const float*)d_in[10];
  const float* fcsr_w = (const float*)d_in[11];
  const float* red_w  = (const float*)d_in[12];
  const float* red_b  = (const float*)d_in[13];
  const float* rec_w  = (const float*)d_in[14];
  const float* rec_b  = (const float*)d_in[15];
  const float* cde_w1 = (const float*)d_in[16];
  const float* cde_b1 = (const float*)d_in[17];
  const float* cde_w2 = (const float*)d_in[18];
  const float* cde_b2 = (const float*)d_in[19];
  const float* init_w = (const float*)d_in[20];
  const float* init_b = (const float*)d_in[21];
  // d_in[22]: w (edge weights) — dead code
  const float* times  = (const float*)d_in[23];
  const int* iid    = (const int*)d_in[24];
  // d_in[25..27]: src,dst,seg_ids — dead / implied by layout
  const int* last_nodes = (const int*)d_in[28];
  const int* embeds_ids = (const int*)d_in[29];
  float* out = (float*)d_out;

  float* ws  = (float*)d_ws;
  float* te  = ws;                    // B*D = 65,536 f
  float* sr  = te + (size_t)BB*DD;    // B*D = 65,536 f
  float* lse = sr + (size_t)BB*DD;    // B   =     512 f   (total 526 KB)

  k_cde   <<<BB/2, 576, 0, stream>>>(emb, embeds_ids, times, red_w, red_b,
                                     cde_w1, cde_b1, cde_w2, cde_b2,
                                     init_w, init_b, rec_w, rec_b, te);
  k_attn  <<<BB, 128, 0, stream>>>(emb, iid, last_nodes, fcu_w, fcv_w, fcv_b,
                                   fce_w, fcsr_w, te, sr);
  k_logits<<<dim3((VN+255)/256, 2), 256, 0, stream>>>(emb, sr, out);
  k_lse   <<<BB, 256, 0, stream>>>(out, lse);
  k_sub   <<<(int)(((size_t)BB*VN/4+255)/256), 256, 0, stream>>>(out, lse);
}